// Round 10
// baseline (404.407 us; speedup 1.0000x reference)
//
#include <hip/hip_runtime.h>
#include <math.h>

#define CIN    128
#define HID    128
#define HDIM   64
#define WDIM   64
#define HW     4096
#define NBATCH 16
#define LROW   136                  // shorts per LDS row (272 B, b128-aligned)
#define WXSZ   (4 * 8 * 64 * 8)    // 16384 shorts per he-slice (x-part frag)
#define WHSZ   (4 * 12 * 64 * 8)   // 24576 shorts per he-slice (h-part frag, ch-grouped)
#define HTWORDS (2 * NBATCH * WDIM * HID)  // 262144 tagged u32 per copy

typedef short short8 __attribute__((ext_vector_type(8)));
typedef float f32x4  __attribute__((ext_vector_type(4)));
typedef unsigned int u32x4 __attribute__((ext_vector_type(4)));

// fallback: agent scope (sc0+sc1 -> MALL coherence point), placement-independent
#define ALOADA(p)     __hip_atomic_load((p), __ATOMIC_RELAXED, __HIP_MEMORY_SCOPE_AGENT)
#define ASTOREA(p, v) __hip_atomic_store((p), (v), __ATOMIC_RELAXED, __HIP_MEMORY_SCOPE_AGENT)

__device__ __forceinline__ unsigned short f2bf(float f) {
    union { float f; unsigned int u; } v; v.f = f;
    unsigned int r = v.u + 0x7fffu + ((v.u >> 16) & 1u);   // RNE
    return (unsigned short)(r >> 16);
}
__device__ __forceinline__ float sigm(float x)  { return 1.0f / (1.0f + __expf(-x)); }
__device__ __forceinline__ float tanhft(float x){ return 2.0f / (1.0f + __expf(-2.0f * x)) - 1.0f; }

// sc0 store: bypass L1, land in XCD-local L2 (visible to same-XCD sc0 loads)
__device__ __forceinline__ void st_sc0(unsigned* p, unsigned v) {
    asm volatile("global_store_dword %0, %1, off sc0" :: "v"(p), "v"(v) : "memory");
}

// 9 L1-bypassing (sc0) loads, one waitcnt: L2-coherent poll of partner writes.
__device__ __forceinline__ void ld9_sc0(unsigned v[9], const unsigned* const p[9]) {
    asm volatile(
        "global_load_dword %0, %9,  off sc0\n\t"
        "global_load_dword %1, %10, off sc0\n\t"
        "global_load_dword %2, %11, off sc0\n\t"
        "global_load_dword %3, %12, off sc0\n\t"
        "global_load_dword %4, %13, off sc0\n\t"
        "global_load_dword %5, %14, off sc0\n\t"
        "global_load_dword %6, %15, off sc0\n\t"
        "global_load_dword %7, %16, off sc0\n\t"
        "global_load_dword %8, %17, off sc0\n\t"
        "s_waitcnt vmcnt(0)"
        : "=&v"(v[0]), "=&v"(v[1]), "=&v"(v[2]), "=&v"(v[3]), "=&v"(v[4]),
          "=&v"(v[5]), "=&v"(v[6]), "=&v"(v[7]), "=&v"(v[8])
        : "v"(p[0]), "v"(p[1]), "v"(p[2]), "v"(p[3]), "v"(p[4]),
          "v"(p[5]), "v"(p[6]), "v"(p[7]), "v"(p[8])
        : "memory");
}

// ---------------------------------------------------------------------------
// Pack: Wx / Wh fragment order (Wh ch-grouped: ks = grp*3 + t), bias fold,
// zero BOTH tag buffers + the XCD slot-claim table (replay/graph safe).
// ---------------------------------------------------------------------------
__global__ void pack_kernel(const float* __restrict__ W_is,
                            const float* __restrict__ b_is,
                            const float* __restrict__ W_ss,
                            const float* __restrict__ b_ss,
                            unsigned short* __restrict__ Wx,
                            unsigned short* __restrict__ Wh,
                            float* __restrict__ bias_p,
                            unsigned int* __restrict__ htF,
                            unsigned int* __restrict__ htA,
                            unsigned int* __restrict__ taken) {
    int idx = blockIdx.x * blockDim.x + threadIdx.x;
    if (idx < 131072) {                 // 8 he * WXSZ
        int j = idx & 7, lane = (idx >> 3) & 63, rest = idx >> 9;
        int ks = rest & 7, gg = rest >> 3, gate = gg & 3, he = gg >> 2;
        int n = gate * 128 + he * 16 + (lane & 15);
        int k = ks * 32 + ((lane >> 4) * 8) + j;        // k = t*128 + c
        Wx[idx] = f2bf(W_is[((size_t)n * CIN + (k & 127)) * 3 + (k >> 7)]);
    }
    if (idx < 196608) {                 // 8 he * WHSZ
        int j = idx & 7, lane = (idx >> 3) & 63, rest = idx >> 9;   // rest < 384
        int ks = rest % 12, gg = rest / 12, gate = gg & 3, he = gg >> 2;
        int grp = ks / 3, t = ks - 3 * grp;
        int c = grp * 32 + ((lane >> 4) * 8) + j;
        int n = gate * 128 + he * 16 + (lane & 15);
        Wh[idx] = f2bf(W_ss[((size_t)n * HID + c) * 3 + t]);
    }
    if (idx < 512) bias_p[idx] = b_is[idx] + b_ss[idx];
    if (idx < 128) taken[idx] = 0u;
    if (idx < HTWORDS) { htF[idx] = 0u; htA[idx] = 0u; }
}

// ---------------------------------------------------------------------------
// xt: x [b][c][r][w] f32 -> xT [b][r][w][c] bf16 (coalesced both sides)
// ---------------------------------------------------------------------------
__global__ __launch_bounds__(256) void xt_kernel(const float* __restrict__ x,
                                                 unsigned int* __restrict__ xT32) {
    __shared__ unsigned short t[128 * 66];
    const int tid = threadIdx.x;
    const int b = blockIdx.x >> 6;
    const int r = blockIdx.x & 63;
#pragma unroll
    for (int i = 0; i < 32; ++i) {
        int flat = i * 256 + tid;
        int c = flat >> 6, w = flat & 63;
        t[c * 66 + w] = f2bf(x[(((size_t)b * 128 + c) * 64 + r) * 64 + w]);
    }
    __syncthreads();
    unsigned* o = xT32 + ((size_t)(b * 64 + r) * 64) * 64;
#pragma unroll
    for (int i = 0; i < 16; ++i) {
        int flat = i * 256 + tid;
        int w = flat >> 6, cp = flat & 63;
        o[w * 64 + cp] = (unsigned)t[(2 * cp) * 66 + w]
                       | ((unsigned)t[(2 * cp + 1) * 66 + w] << 16);
    }
}

// ---------------------------------------------------------------------------
// Persistent LSTM: grid 128, 1 blk/CU, fully wave-autonomous.
// XCD-AWARE SLOT CLAIMING: slot s = b*8+he; XCD x preferentially owns slots
// of batches {2x, 2x+1} (s in [x*16, x*16+16)). Each block reads its physical
// HW_REG_XCC_ID and CAS-claims a local slot, global scan as overflow. =>
// the 8 partner blocks of a batch are co-XCD whenever the scheduler puts
// ~16 blocks per XCD; then the tagged handshake runs through the SHARED
// XCD L2: publish via sc0 stores, poll via sc0 loads (~250cyc RT instead of
// ~1us MALL). Split groups degrade per-wave to the agent copy (sticky pmode),
// so correctness is placement-independent. Tag protocol unchanged
// (word = bf16<<16 | r+1, parity ping-pong, word atomicity).
// ---------------------------------------------------------------------------
__global__ __launch_bounds__(256, 1) void lstm_kernel(
        const unsigned int* __restrict__ xT32,
        const unsigned short* __restrict__ Wx,
        const unsigned short* __restrict__ Wh,
        const float* __restrict__ bias_p,
        unsigned int* htF,
        unsigned int* htA,
        unsigned int* taken,
        float* __restrict__ out) {
    __shared__ __align__(16) unsigned short lds_bx[WXSZ];           // 32 KiB
    __shared__ __align__(16) unsigned short lds_bh[WHSZ];           // 48 KiB
    __shared__ __align__(16) unsigned short ldsx[4][2][17 * LROW];  // 36.1 KiB
    __shared__ __align__(16) unsigned short ldsh[4][2][18 * LROW];  // 38.25 KiB
    __shared__ int sh_slot;

    const int tid  = threadIdx.x;
    const int wv   = tid >> 6;
    const int lane = tid & 63;
    const int quad = lane >> 4;
    const int l15  = lane & 15;

    // ---- claim a (b, he) slot with XCD affinity ----
    if (tid == 0) {
        unsigned xcc;
        asm volatile("s_getreg_b32 %0, hwreg(HW_REG_XCC_ID)" : "=s"(xcc));
        int x = (int)(xcc & 7u);
        int slot = -1;
        for (int i = 0; i < 16 && slot < 0; ++i) {
            int s = x * 16 + i;
            if (atomicCAS(&taken[s], 0u, 1u) == 0u) slot = s;
        }
        for (int s = 0; s < 128 && slot < 0; ++s)
            if (atomicCAS(&taken[s], 0u, 1u) == 0u) slot = s;
        sh_slot = slot;
    }
    __syncthreads();
    const int b  = sh_slot >> 3;           // slot = b*8 + he
    const int he = sh_slot & 7;

    // ---- prologue: weight slices -> LDS (block-coop, once) ----
    {
        const u32x4* src = (const u32x4*)(Wx + (size_t)he * WXSZ);
        u32x4* dst = (u32x4*)lds_bx;
#pragma unroll
        for (int p = 0; p < 8; ++p) dst[p * 256 + tid] = src[p * 256 + tid];
        const u32x4* srh = (const u32x4*)(Wh + (size_t)he * WHSZ);
        u32x4* dsh = (u32x4*)lds_bh;
#pragma unroll
        for (int p = 0; p < 12; ++p) dsh[p * 256 + tid] = srh[p * 256 + tid];
    }

#define STAGE_XW(ROW, XP)                                                      \
    {                                                                          \
        const unsigned* xs = xT32 + ((size_t)(b * 64 + (ROW)) * 64) * 64;      \
        _Pragma("unroll")                                                      \
        for (int i = 0; i < 17; ++i) {                                         \
            int rr = wv * 16 - 1 + i;                                          \
            unsigned v = (rr >= 0) ? xs[rr * 64 + lane] : 0u;                  \
            ((unsigned*)(XP))[i * 68 + lane] = v;                              \
        }                                                                      \
    }

#define GEMM_XW(XP)                                                            \
    {                                                                          \
        _Pragma("unroll")                                                      \
        for (int ks = 0; ks < 8; ++ks) {                                       \
            const int t = ks >> 2, c0 = (ks & 3) * 32;                         \
            short8 a = *(const short8*)&(XP)[(l15 + t) * LROW + c0 + quad * 8];\
            _Pragma("unroll")                                                  \
            for (int g = 0; g < 4; ++g) {                                      \
                short8 bq = *(const short8*)&lds_bx[((g * 8 + ks) * 64 + lane) * 8]; \
                acc[g] = __builtin_amdgcn_mfma_f32_16x16x32_bf16(a, bq, acc[g], 0, 0, 0); \
            }                                                                  \
        }                                                                      \
    }

// agent-scope 9-word try (fallback path); sets hv_, diff
#define TRY9A(HS)                                                              \
    {                                                                          \
        diff = 0u;                                                             \
        _Pragma("unroll")                                                      \
        for (int i = 0; i < 9; ++i) {                                          \
            int wi = i * 64 + lane;                                            \
            int row_i = wi >> 5, ch32 = wi & 31;                               \
            int rr = wv * 16 - 1 + row_i;                                      \
            unsigned v = ((unsigned)rr < 64u)                                  \
                ? ALOADA(&(HS)[rr * 128 + grpc + ch32])                        \
                : want;                                                        \
            hv_[i] = v;                                                        \
            diff |= (v ^ want) & 0xffffu;                                      \
        }                                                                      \
    }

// one 32-ch group: sc0-L2 poll (agent fallback) -> private LDS stage -> GEMM
#define HGRP(GRP, WANT, HSF, HSA, HP)                                          \
    {                                                                          \
        const int grpc = (GRP) * 32;                                           \
        const unsigned want = (unsigned)(WANT);                                \
        unsigned hv_[9]; unsigned diff;                                        \
        const unsigned* pp[9]; unsigned okm[9];                                \
        _Pragma("unroll")                                                      \
        for (int i = 0; i < 9; ++i) {                                          \
            int wi = i * 64 + lane;                                            \
            int row_i = wi >> 5, ch32 = wi & 31;                               \
            int rr = wv * 16 - 1 + row_i;                                      \
            int rc = rr < 0 ? 0 : (rr > 63 ? 63 : rr);                         \
            pp[i]  = &(HSF)[rc * 128 + grpc + ch32];                           \
            okm[i] = ((unsigned)rr < 64u) ? 0xffffffffu : 0u;                  \
        }                                                                      \
        __builtin_amdgcn_s_setprio(0);                                         \
        if (pmode == 0) {                                                      \
            int tries = 0;                                                     \
            for (;;) {                                                         \
                ld9_sc0(hv_, pp);                                              \
                diff = 0u;                                                     \
                _Pragma("unroll")                                              \
                for (int i = 0; i < 9; ++i) {                                  \
                    hv_[i] = (hv_[i] & okm[i]) | (want & ~okm[i]);             \
                    diff |= (hv_[i] ^ want) & 0xffffu;                         \
                }                                                              \
                if (__ballot(diff != 0u) == 0ull) break;                       \
                if (++tries >= 16) {                                           \
                    TRY9A(HSA);                                                \
                    if (__ballot(diff != 0u) == 0ull) { pmode = 1; break; }    \
                    tries = 0;                                                 \
                }                                                              \
            }                                                                  \
        } else {                                                               \
            for (;;) {                                                         \
                TRY9A(HSA);                                                    \
                if (__ballot(diff != 0u) == 0ull) break;                       \
            }                                                                  \
        }                                                                      \
        __builtin_amdgcn_s_setprio(1);                                         \
        _Pragma("unroll")                                                      \
        for (int i = 0; i < 9; ++i) {                                          \
            int wi = i * 64 + lane;                                            \
            int row_i = wi >> 5, ch32 = wi & 31;                               \
            (HP)[row_i * LROW + grpc + ch32] = (unsigned short)(hv_[i] >> 16); \
        }                                                                      \
        _Pragma("unroll")                                                      \
        for (int t = 0; t < 3; ++t) {                                          \
            const int ks = (GRP) * 3 + t;                                      \
            short8 a = *(const short8*)&(HP)[(l15 + t) * LROW + grpc + quad * 8]; \
            _Pragma("unroll")                                                  \
            for (int g = 0; g < 4; ++g) {                                      \
                short8 bq = *(const short8*)&lds_bh[((g * 12 + ks) * 64 + lane) * 8]; \
                acc[g] = __builtin_amdgcn_mfma_f32_16x16x32_bf16(a, bq, acc[g], 0, 0, 0); \
            }                                                                  \
        }                                                                      \
    }

    STAGE_XW(0, ldsx[wv][0]);            // per-wave x row 0
    __syncthreads();                     // weights ready
    __builtin_amdgcn_s_setprio(1);

    const int hch = he * 16 + l15;
    const float bi  = bias_p[      hch];
    const float bf_ = bias_p[128 + hch];
    const float bo  = bias_p[256 + hch];
    const float bg  = bias_p[384 + hch];

    f32x4 creg = (f32x4){0.f, 0.f, 0.f, 0.f};
    int pmode = 0;                        // 0 = sc0/L2 fast path, 1 = agent fallback

    for (int r = 0; r < HDIM; ++r) {
        f32x4 acc[4];
#pragma unroll
        for (int g = 0; g < 4; ++g) acc[g] = (f32x4){0.f, 0.f, 0.f, 0.f};

        if (r < HDIM - 1) STAGE_XW(r + 1, ldsx[wv][(r + 1) & 1]);  // overlap
        GEMM_XW(ldsx[wv][r & 1]);                                   // x-part

        if (r > 0) {
            const size_t hoff = ((size_t)((r - 1) & 1) * NBATCH + b) * (WDIM * HID);
            const unsigned* hsf = htF + hoff;
            const unsigned* hsa = htA + hoff;
            unsigned short* hp = ldsh[wv][(r - 1) & 1];
            HGRP(0, r, hsf, hsa, hp);
            HGRP(1, r, hsf, hsa, hp);
            HGRP(2, r, hsf, hsa, hp);
            HGRP(3, r, hsf, hsa, hp);
        }

        // ---- epilogue: publish fast(sc0) -> agent -> out (HBM write last) ----
        {
            const int w0 = wv * 16 + quad * 4;
            f32x4 hv;
#pragma unroll
            for (int e = 0; e < 4; ++e) {
                float zi = acc[0][e] + bi;
                float zf = acc[1][e] + bf_;
                float zo = acc[2][e] + bo;
                float zg = acc[3][e] + bg;
                float ig = sigm(zi), fg = sigm(zf), og = sigm(zo);
                float gg = tanhft(zg);
                float cn = fg * creg[e] + ig * gg;
                creg[e] = cn;
                hv[e]   = og * tanhft(cn);
            }
            const size_t hoff = ((size_t)(r & 1) * NBATCH + b) * (WDIM * HID);
            unsigned w_[4];
#pragma unroll
            for (int e = 0; e < 4; ++e)
                w_[e] = ((unsigned)f2bf(hv[e]) << 16) | (unsigned)(r + 1);
#pragma unroll
            for (int e = 0; e < 4; ++e)
                st_sc0(&htF[hoff + (w0 + e) * 128 + hch], w_[e]);
#pragma unroll
            for (int e = 0; e < 4; ++e)
                ASTOREA(&htA[hoff + (w0 + e) * 128 + hch], w_[e]);
            *(f32x4*)&out[(((size_t)b * HID + hch) * HDIM + r) * WDIM + w0] = hv;
        }
    }
}

extern "C" void kernel_launch(void* const* d_in, const int* in_sizes, int n_in,
                              void* d_out, int out_size, void* d_ws, size_t ws_size,
                              hipStream_t stream) {
    const float* x    = (const float*)d_in[0];
    const float* W_is = (const float*)d_in[1];
    const float* b_is = (const float*)d_in[2];
    const float* W_ss = (const float*)d_in[3];
    const float* b_ss = (const float*)d_in[4];
    float* out = (float*)d_out;

    // ws: xT bf16[16][64][64][128] | htF | htA | Wx | Wh | bias | taken[128]
    const size_t XT_BYTES = (size_t)16 * 64 * 64 * 128 * 2;   // 16777216
    const size_t HT_BYTES = (size_t)HTWORDS * 4;              //  1048576
    const size_t WX_BYTES = 8 * WXSZ * 2;                     //   262144
    const size_t WH_BYTES = 8 * WHSZ * 2;                     //   393216

    unsigned int*   xT32   = (unsigned int*)d_ws;
    unsigned int*   htF    = (unsigned int*)((char*)d_ws + XT_BYTES);
    unsigned int*   htA    = (unsigned int*)((char*)d_ws + XT_BYTES + HT_BYTES);
    unsigned short* Wx     = (unsigned short*)((char*)d_ws + XT_BYTES + 2 * HT_BYTES);
    unsigned short* Wh     = (unsigned short*)((char*)d_ws + XT_BYTES + 2 * HT_BYTES + WX_BYTES);
    float*          bias_p = (float*)((char*)d_ws + XT_BYTES + 2 * HT_BYTES + WX_BYTES + WH_BYTES);
    unsigned int*   taken  = (unsigned int*)((char*)d_ws + XT_BYTES + 2 * HT_BYTES + WX_BYTES + WH_BYTES + 2048);

    pack_kernel<<<1024, 256, 0, stream>>>(W_is, b_is, W_ss, b_ss, Wx, Wh, bias_p, htF, htA, taken);
    xt_kernel<<<1024, 256, 0, stream>>>(x, xT32);
    lstm_kernel<<<128, 256, 0, stream>>>(xT32, Wx, Wh, bias_p, htF, htA, taken, out);
}

// Round 11
// 318.066 us; speedup vs baseline: 1.2715x; 1.2715x over previous
//
#include <hip/hip_runtime.h>
#include <math.h>

#define CIN    128
#define HID    128
#define HDIM   64
#define WDIM   64
#define HW     4096
#define NBATCH 16
#define LROW   136                  // shorts per LDS row (272 B, b128-aligned)
#define WXSZ   (4 * 8 * 64 * 8)    // 16384 shorts per he-slice (x-part frag)
#define WHSZ   (4 * 12 * 64 * 8)   // 24576 shorts per he-slice (h-part frag, ch-grouped)
#define HTWORDS (2 * NBATCH * WDIM * HID)  // 262144 tagged u32

typedef short short8 __attribute__((ext_vector_type(8)));
typedef float f32x4  __attribute__((ext_vector_type(4)));
typedef unsigned int u32x4 __attribute__((ext_vector_type(4)));

// agent scope (sc0+sc1 -> MALL coherence point)
#define ASTOREA(p, v) __hip_atomic_store((p), (v), __ATOMIC_RELAXED, __HIP_MEMORY_SCOPE_AGENT)

__device__ __forceinline__ unsigned short f2bf(float f) {
    union { float f; unsigned int u; } v; v.f = f;
    unsigned int r = v.u + 0x7fffu + ((v.u >> 16) & 1u);   // RNE
    return (unsigned short)(r >> 16);
}
__device__ __forceinline__ float sigm(float x)  { return 1.0f / (1.0f + __expf(-x)); }
__device__ __forceinline__ float tanhft(float x){ return 2.0f / (1.0f + __expf(-2.0f * x)) - 1.0f; }

// issue 9 MALL-coherent loads, NO wait (software-pipelined poll issue)
__device__ __forceinline__ void ld9_issue(unsigned v[9], const unsigned* const p[9]) {
    asm volatile(
        "global_load_dword %0, %9,  off sc0 sc1\n\t"
        "global_load_dword %1, %10, off sc0 sc1\n\t"
        "global_load_dword %2, %11, off sc0 sc1\n\t"
        "global_load_dword %3, %12, off sc0 sc1\n\t"
        "global_load_dword %4, %13, off sc0 sc1\n\t"
        "global_load_dword %5, %14, off sc0 sc1\n\t"
        "global_load_dword %6, %15, off sc0 sc1\n\t"
        "global_load_dword %7, %16, off sc0 sc1\n\t"
        "global_load_dword %8, %17, off sc0 sc1"
        : "=&v"(v[0]), "=&v"(v[1]), "=&v"(v[2]), "=&v"(v[3]), "=&v"(v[4]),
          "=&v"(v[5]), "=&v"(v[6]), "=&v"(v[7]), "=&v"(v[8])
        : "v"(p[0]), "v"(p[1]), "v"(p[2]), "v"(p[3]), "v"(p[4]),
          "v"(p[5]), "v"(p[6]), "v"(p[7]), "v"(p[8])
        : "memory");
}
// consume point: wait all outstanding vmem; ties the 9 regs so uses come after
__device__ __forceinline__ void wait9(unsigned v[9]) {
    asm volatile("s_waitcnt vmcnt(0)"
        : "+v"(v[0]), "+v"(v[1]), "+v"(v[2]), "+v"(v[3]), "+v"(v[4]),
          "+v"(v[5]), "+v"(v[6]), "+v"(v[7]), "+v"(v[8]) :: "memory");
}

// ---------------------------------------------------------------------------
// Pack: Wx / Wh fragment order (Wh ch-grouped: ks = grp*3 + t), bias fold,
// zero the tag buffer (replay/graph safe).
// ---------------------------------------------------------------------------
__global__ void pack_kernel(const float* __restrict__ W_is,
                            const float* __restrict__ b_is,
                            const float* __restrict__ W_ss,
                            const float* __restrict__ b_ss,
                            unsigned short* __restrict__ Wx,
                            unsigned short* __restrict__ Wh,
                            float* __restrict__ bias_p,
                            unsigned int* __restrict__ ht) {
    int idx = blockIdx.x * blockDim.x + threadIdx.x;
    if (idx < 131072) {                 // 8 he * WXSZ
        int j = idx & 7, lane = (idx >> 3) & 63, rest = idx >> 9;
        int ks = rest & 7, gg = rest >> 3, gate = gg & 3, he = gg >> 2;
        int n = gate * 128 + he * 16 + (lane & 15);
        int k = ks * 32 + ((lane >> 4) * 8) + j;        // k = t*128 + c
        Wx[idx] = f2bf(W_is[((size_t)n * CIN + (k & 127)) * 3 + (k >> 7)]);
    }
    if (idx < 196608) {                 // 8 he * WHSZ
        int j = idx & 7, lane = (idx >> 3) & 63, rest = idx >> 9;   // rest < 384
        int ks = rest % 12, gg = rest / 12, gate = gg & 3, he = gg >> 2;
        int grp = ks / 3, t = ks - 3 * grp;
        int c = grp * 32 + ((lane >> 4) * 8) + j;
        int n = gate * 128 + he * 16 + (lane & 15);
        Wh[idx] = f2bf(W_ss[((size_t)n * HID + c) * 3 + t]);
    }
    if (idx < 512) bias_p[idx] = b_is[idx] + b_ss[idx];
    if (idx < HTWORDS) ht[idx] = 0u;
}

// ---------------------------------------------------------------------------
// xt: x [b][c][r][w] f32 -> xT [b][r][w][c] bf16 (coalesced both sides)
// ---------------------------------------------------------------------------
__global__ __launch_bounds__(256) void xt_kernel(const float* __restrict__ x,
                                                 unsigned int* __restrict__ xT32) {
    __shared__ unsigned short t[128 * 66];
    const int tid = threadIdx.x;
    const int b = blockIdx.x >> 6;
    const int r = blockIdx.x & 63;
#pragma unroll
    for (int i = 0; i < 32; ++i) {
        int flat = i * 256 + tid;
        int c = flat >> 6, w = flat & 63;
        t[c * 66 + w] = f2bf(x[(((size_t)b * 128 + c) * 64 + r) * 64 + w]);
    }
    __syncthreads();
    unsigned* o = xT32 + ((size_t)(b * 64 + r) * 64) * 64;
#pragma unroll
    for (int i = 0; i < 16; ++i) {
        int flat = i * 256 + tid;
        int w = flat >> 6, cp = flat & 63;
        o[w * 64 + cp] = (unsigned)t[(2 * cp) * 66 + w]
                       | ((unsigned)t[(2 * cp + 1) * 66 + w] << 16);
    }
}

// ---------------------------------------------------------------------------
// Persistent LSTM: grid 128 = (b, he), 1 blk/CU, wave-autonomous, tagged
// agent-scope h words (bf16<<16 | r+1), parity ping-pong — R7 protocol,
// but with SOFTWARE-PIPELINED POLLS: group g+1's 9 tag-loads are ISSUED
// before group g's stage+GEMM, so each MALL round-trip hides under ~500cy
// of real work; only G0's RT is exposed (and it issues before GEMM_X).
// x-stage is register-split: loads at row top, ds_write at row bottom
// (GEMM_X no longer gated by the stage's vmcnt/lgkm chain).
// Stale early reads fail the tag check and re-spin (rare in steady state).
// ---------------------------------------------------------------------------
__global__ __launch_bounds__(256, 1) void lstm_kernel(
        const unsigned int* __restrict__ xT32,
        const unsigned short* __restrict__ Wx,
        const unsigned short* __restrict__ Wh,
        const float* __restrict__ bias_p,
        unsigned int* ht,
        float* __restrict__ out) {
    __shared__ __align__(16) unsigned short lds_bx[WXSZ];           // 32 KiB
    __shared__ __align__(16) unsigned short lds_bh[WHSZ];           // 48 KiB
    __shared__ __align__(16) unsigned short ldsx[4][2][17 * LROW];  // 36.1 KiB
    __shared__ __align__(16) unsigned short ldsh[4][18 * LROW];     // 19.1 KiB

    const int tid  = threadIdx.x;
    const int b    = blockIdx.x & 15;
    const int he   = blockIdx.x >> 4;
    const int wv   = tid >> 6;
    const int lane = tid & 63;
    const int quad = lane >> 4;
    const int l15  = lane & 15;

    // ---- prologue: weight slices -> LDS (block-coop, once) ----
    {
        const u32x4* src = (const u32x4*)(Wx + (size_t)he * WXSZ);
        u32x4* dst = (u32x4*)lds_bx;
#pragma unroll
        for (int p = 0; p < 8; ++p) dst[p * 256 + tid] = src[p * 256 + tid];
        const u32x4* srh = (const u32x4*)(Wh + (size_t)he * WHSZ);
        u32x4* dsh = (u32x4*)lds_bh;
#pragma unroll
        for (int p = 0; p < 12; ++p) dsh[p * 256 + tid] = srh[p * 256 + tid];
    }

    // per-lane poll geometry: word i covers (row_i, ch32_i); rows clamped,
    // halo rows masked (tag substituted with `want`, data -> bf16 0)
    int  hoffw[9];      // word offset rc*128 + ch32 (group adds g*32)
    unsigned okm[9];
#pragma unroll
    for (int i = 0; i < 9; ++i) {
        int wi = i * 64 + lane;
        int row_i = wi >> 5, ch32 = wi & 31;
        int rr = wv * 16 - 1 + row_i;
        int rc = rr < 0 ? 0 : (rr > 63 ? 63 : rr);
        hoffw[i] = rc * 128 + ch32;
        okm[i]   = ((unsigned)rr < 64u) ? 0xffffffffu : 0u;
    }

#define HPTRS(PP, HS, GRP)                                                     \
    _Pragma("unroll")                                                          \
    for (int i = 0; i < 9; ++i) (PP)[i] = (HS) + hoffw[i] + (GRP) * 32;

#define HCHECK(HV, WANT, DIFF)                                                 \
    {                                                                          \
        (DIFF) = 0u;                                                           \
        _Pragma("unroll")                                                      \
        for (int i = 0; i < 9; ++i) {                                          \
            (HV)[i] = ((HV)[i] & okm[i]) | ((WANT) & ~okm[i]);                 \
            (DIFF) |= ((HV)[i] ^ (WANT)) & 0xffffu;                            \
        }                                                                      \
    }

#define HSPIN(HV, PP, WANT)                                                    \
    {                                                                          \
        __builtin_amdgcn_s_setprio(0);                                         \
        for (;;) {                                                             \
            ld9_issue((HV), (PP)); wait9((HV));                                \
            unsigned d_; HCHECK((HV), (WANT), d_);                             \
            if (__ballot(d_ != 0u) == 0ull) break;                             \
        }                                                                      \
        __builtin_amdgcn_s_setprio(1);                                         \
    }

#define HSTAGE(HV, GRP, HP)                                                    \
    _Pragma("unroll")                                                          \
    for (int i = 0; i < 9; ++i) {                                              \
        int wi = i * 64 + lane;                                                \
        (HP)[(wi >> 5) * LROW + (GRP) * 32 + (wi & 31)] =                      \
            (unsigned short)((HV)[i] >> 16);                                   \
    }

#define HGEMM(GRP, HP)                                                         \
    _Pragma("unroll")                                                          \
    for (int t = 0; t < 3; ++t) {                                              \
        const int ks = (GRP) * 3 + t;                                          \
        short8 a = *(const short8*)&(HP)[(l15 + t) * LROW + (GRP) * 32 + quad * 8]; \
        _Pragma("unroll")                                                      \
        for (int g = 0; g < 4; ++g) {                                          \
            short8 bq = *(const short8*)&lds_bh[((g * 12 + ks) * 64 + lane) * 8]; \
            acc[g] = __builtin_amdgcn_mfma_f32_16x16x32_bf16(a, bq, acc[g], 0, 0, 0); \
        }                                                                      \
    }

#define GEMM_XW(XP)                                                            \
    _Pragma("unroll")                                                          \
    for (int ks = 0; ks < 8; ++ks) {                                           \
        const int t = ks >> 2, c0 = (ks & 3) * 32;                             \
        short8 a = *(const short8*)&(XP)[(l15 + t) * LROW + c0 + quad * 8];    \
        _Pragma("unroll")                                                      \
        for (int g = 0; g < 4; ++g) {                                          \
            short8 bq = *(const short8*)&lds_bx[((g * 8 + ks) * 64 + lane) * 8]; \
            acc[g] = __builtin_amdgcn_mfma_f32_16x16x32_bf16(a, bq, acc[g], 0, 0, 0); \
        }                                                                      \
    }

    // initial x stage (row 0) straight to LDS
    {
        const unsigned* xs = xT32 + ((size_t)(b * 64 + 0) * 64) * 64;
#pragma unroll
        for (int i = 0; i < 17; ++i) {
            int rr = wv * 16 - 1 + i;
            ((unsigned*)ldsx[wv][0])[i * 68 + lane] = (rr >= 0) ? xs[rr * 64 + lane] : 0u;
        }
    }
    __syncthreads();                     // weights + x0 ready (only barrier)
    __builtin_amdgcn_s_setprio(1);

    const int hch = he * 16 + l15;
    const float bi  = bias_p[      hch];
    const float bf_ = bias_p[128 + hch];
    const float bo  = bias_p[256 + hch];
    const float bg  = bias_p[384 + hch];

    f32x4 creg = (f32x4){0.f, 0.f, 0.f, 0.f};

    for (int r = 0; r < HDIM; ++r) {
        const unsigned want = (unsigned)r;
        const unsigned* hs = ht + ((size_t)((r - 1) & 1) * NBATCH + b) * (WDIM * HID);
        unsigned short* hp = ldsh[wv];

        // issue G0 poll loads first (RT hides under x prefetch + GEMM_X)
        unsigned hva[9], hvb[9];
        const unsigned* ppa[9]; const unsigned* ppb[9];
        if (r > 0) { HPTRS(ppa, hs, 0); ld9_issue(hva, ppa); }

        // x prefetch for r+1 into registers (ds_write deferred to row end)
        unsigned xr[17];
        if (r < HDIM - 1) {
            const unsigned* xs = xT32 + ((size_t)(b * 64 + r + 1) * 64) * 64;
#pragma unroll
            for (int i = 0; i < 17; ++i) {
                int rr = wv * 16 - 1 + i;
                xr[i] = (rr >= 0) ? xs[rr * 64 + lane] : 0u;
            }
        }

        f32x4 acc[4];
#pragma unroll
        for (int g = 0; g < 4; ++g) acc[g] = (f32x4){0.f, 0.f, 0.f, 0.f};

        GEMM_XW(ldsx[wv][r & 1]);                          // x-part of row r

        if (r > 0) {
            unsigned diff;
            // --- G0: consume (RT already spent under GEMM_X) ---
            wait9(hva); HCHECK(hva, want, diff);
            if (__ballot(diff != 0u) != 0ull) HSPIN(hva, ppa, want);
            HPTRS(ppb, hs, 1); ld9_issue(hvb, ppb);        // issue G1
            HSTAGE(hva, 0, hp); HGEMM(0, hp);
            // --- G1 ---
            wait9(hvb); HCHECK(hvb, want, diff);
            if (__ballot(diff != 0u) != 0ull) HSPIN(hvb, ppb, want);
            HPTRS(ppa, hs, 2); ld9_issue(hva, ppa);        // issue G2
            HSTAGE(hvb, 1, hp); HGEMM(1, hp);
            // --- G2 ---
            wait9(hva); HCHECK(hva, want, diff);
            if (__ballot(diff != 0u) != 0ull) HSPIN(hva, ppa, want);
            HPTRS(ppb, hs, 3); ld9_issue(hvb, ppb);        // issue G3
            HSTAGE(hva, 2, hp); HGEMM(2, hp);
            // --- G3 ---
            wait9(hvb); HCHECK(hvb, want, diff);
            if (__ballot(diff != 0u) != 0ull) HSPIN(hvb, ppb, want);
            HSTAGE(hvb, 3, hp); HGEMM(3, hp);
        }

        // ---- epilogue: gates lane-local; publish each h word ASAP ----
        {
            const int w0 = wv * 16 + quad * 4;
            unsigned* hb = ht + ((size_t)(r & 1) * NBATCH + b) * (WDIM * HID);
            f32x4 hv;
#pragma unroll
            for (int e = 0; e < 4; ++e) {
                float zi = acc[0][e] + bi;
                float zf = acc[1][e] + bf_;
                float zo = acc[2][e] + bo;
                float zg = acc[3][e] + bg;
                float ig = sigm(zi), fg = sigm(zf), og = sigm(zo);
                float gg = tanhft(zg);
                float cn = fg * creg[e] + ig * gg;
                creg[e] = cn;
                hv[e]   = og * tanhft(cn);
                ASTOREA(&hb[(w0 + e) * 128 + hch],
                        ((unsigned)f2bf(hv[e]) << 16) | (unsigned)(r + 1));
            }
            *(f32x4*)&out[(((size_t)b * HID + hch) * HDIM + r) * WDIM + w0] = hv;
        }

        // deferred x ds_write for row r+1 (off the inter-block critical path)
        if (r < HDIM - 1) {
            unsigned* xp = (unsigned*)ldsx[wv][(r + 1) & 1];
#pragma unroll
            for (int i = 0; i < 17; ++i) xp[i * 68 + lane] = xr[i];
        }
    }
}

extern "C" void kernel_launch(void* const* d_in, const int* in_sizes, int n_in,
                              void* d_out, int out_size, void* d_ws, size_t ws_size,
                              hipStream_t stream) {
    const float* x    = (const float*)d_in[0];
    const float* W_is = (const float*)d_in[1];
    const float* b_is = (const float*)d_in[2];
    const float* W_ss = (const float*)d_in[3];
    const float* b_ss = (const float*)d_in[4];
    float* out = (float*)d_out;

    // ws: xT bf16[16][64][64][128] | ht u32 | Wx | Wh | bias
    const size_t XT_BYTES = (size_t)16 * 64 * 64 * 128 * 2;   // 16777216
    const size_t HT_BYTES = (size_t)HTWORDS * 4;              //  1048576
    const size_t WX_BYTES = 8 * WXSZ * 2;                     //   262144
    const size_t WH_BYTES = 8 * WHSZ * 2;                     //   393216

    unsigned int*   xT32   = (unsigned int*)d_ws;
    unsigned int*   ht     = (unsigned int*)((char*)d_ws + XT_BYTES);
    unsigned short* Wx     = (unsigned short*)((char*)d_ws + XT_BYTES + HT_BYTES);
    unsigned short* Wh     = (unsigned short*)((char*)d_ws + XT_BYTES + HT_BYTES + WX_BYTES);
    float*          bias_p = (float*)((char*)d_ws + XT_BYTES + HT_BYTES + WX_BYTES + WH_BYTES);

    pack_kernel<<<1024, 256, 0, stream>>>(W_is, b_is, W_ss, b_ss, Wx, Wh, bias_p, ht);
    xt_kernel<<<1024, 256, 0, stream>>>(x, xT32);
    lstm_kernel<<<128, 256, 0, stream>>>(xT32, Wx, Wh, bias_p, ht, out);
}